// Round 8
// baseline (130.902 us; speedup 1.0000x reference)
//
#include <hip/hip_runtime.h>

// SparseMCFModel — flow depends only on demands/edge_row/edge_col (GAT/GRU dead).
//   V_1[v] = relu(d[v])/deg[v]
//   V_j[v] = (relu(d[v]) + sum_{e:col=v} V_{j-1}[row_e]) / deg[v],  j=2..10
//   out[e] = V_10[row_e]
//
// r22 = r21 skeleton (48.8us, best measured) + two micro-deltas:
//  (1) 4 roles x 8 slots (CAP 32): a node's roles are lanes 4k..4k+3 of ONE
//      wave -> partial-sum reduce is two __shfl_xor (masks 1,2), removing the
//      LDS part[] buffer and one __syncthreads per round (9x incl. V2 setup).
//      (FP re-grouping safe: r14 role-grouped vs r17 flat-ascending both
//      scored absmax 0.0.)
//  (2) 160 blocks x 125 nodes (160*125 = 20000 exact): +25% CUs for build/out,
//      arrival depth 16 -> 5 (160 arrivals over 32 padded lines).
// POST-MORTEM series: r15/r16 dataflow convoys; r17/r18 small-grid invariance;
//  r19 per-round fence storms; r20 one-fence-pair still +37us, plain-store
//  build saves no write traffic. Coherence rules (r6-r14 proven): cross-block
//  mutable data ONLY via agent-scope atomic ld/st; deg/fill read ld_coh;
//  pcsc st_coh-written, plain-read post-barrier (fresh lines); demands/edge_*
//  immutable -> plain cached. All spins watchdog-bounded.

#define N_NODES 20000
#define N_EDGES 200000
#define NBLK 160
#define NTHR 512
#define NPB 125                            // nodes per block (160*125 = 20000)
#define CAP 32                             // padded in-edge slots (4 roles x 8)
#define NQUAD 50000                        // N_EDGES/4 int4 quads
#define QPB 313                            // quads per block (313*160 = 50080)
#define OFL_MAX 4096
#define NP1 (N_NODES + 1)
#define SPIN_MAX 65536                     // watchdog: never hang, fail loud
#define NLINE 32                           // arrival counter lines (5 deep)

__device__ __forceinline__ float ld_coh(const float* p) {
    return __hip_atomic_load(p, __ATOMIC_RELAXED, __HIP_MEMORY_SCOPE_AGENT);
}
__device__ __forceinline__ int ld_coh_i(const int* p) {
    return __hip_atomic_load(p, __ATOMIC_RELAXED, __HIP_MEMORY_SCOPE_AGENT);
}
__device__ __forceinline__ void st_coh(float* p, float v) {
    __hip_atomic_store(p, v, __ATOMIC_RELAXED, __HIP_MEMORY_SCOPE_AGENT);
}
__device__ __forceinline__ void st_coh_i(int* p, int v) {
    __hip_atomic_store(p, v, __ATOMIC_RELAXED, __HIP_MEMORY_SCOPE_AGENT);
}

// Distributed-arrival barrier: 160 arrivals over 32 padded lines (5 serialized
// RMWs each, lines in parallel); poller sums 32 loads with ILP. Watchdog.
__device__ __forceinline__ void gbar(int* grp, int ord) {
    __syncthreads();
    if (threadIdx.x == 0) {
        __hip_atomic_fetch_add(&grp[(blockIdx.x & (NLINE - 1)) * 32], 1,
                               __ATOMIC_RELAXED, __HIP_MEMORY_SCOPE_AGENT);
        const int target = NBLK * ord;
        for (int t = 0; t < SPIN_MAX; ++t) {
            int s = 0;
            #pragma unroll
            for (int g = 0; g < NLINE; ++g)
                s += __hip_atomic_load(&grp[g * 32], __ATOMIC_RELAXED,
                                       __HIP_MEMORY_SCOPE_AGENT);
            if (s >= target) break;
            __builtin_amdgcn_s_sleep(1);
        }
    }
    __syncthreads();
}

__global__ __launch_bounds__(NTHR)
void mcf_fused(const float* __restrict__ demands,
               const int* __restrict__ edge_row,   // int4-aligned
               const int* __restrict__ edge_col,
               float* __restrict__ out,
               int* __restrict__ deg,       // [N]   zeroed
               int* __restrict__ fill,      // [N]   zeroed
               float* __restrict__ V0,      // [N+1] zeroed
               float* __restrict__ V1b,     // [N+1] zeroed
               int* __restrict__ pcsc,      // [N*CAP]
               int* __restrict__ ofl_cnt,   // [1]   zeroed
               int* __restrict__ ofl_v,     // [OFL_MAX]
               int* __restrict__ ofl_row,   // [OFL_MAX]
               int* __restrict__ grp)       // [NLINE*32] zeroed
{
    const int tx = threadIdx.x, bx = blockIdx.x;
    int bar = 0;

    // ---- Build: int4 edge loads, deg/fill atomics, st_coh pcsc scatter ----
    const int m = bx * QPB + tx;                  // this thread's quad
    const bool bld = (tx < QPB) && (m < NQUAD);
    int4 r4 = {0, 0, 0, 0};
    if (bld) {
        r4 = ((const int4*)edge_row)[m];
        int4 c4 = ((const int4*)edge_col)[m];
        int rr[4] = {r4.x, r4.y, r4.z, r4.w};
        int cc[4] = {c4.x, c4.y, c4.z, c4.w};
        #pragma unroll
        for (int i = 0; i < 4; ++i) {
            __hip_atomic_fetch_add(&deg[rr[i]], 1, __ATOMIC_RELAXED, __HIP_MEMORY_SCOPE_AGENT);
            int idx = __hip_atomic_fetch_add(&fill[cc[i]], 1,
                                             __ATOMIC_RELAXED, __HIP_MEMORY_SCOPE_AGENT);
            if (idx < CAP) {
                st_coh_i(&pcsc[cc[i] * CAP + idx], rr[i]);
            } else {
                int o = __hip_atomic_fetch_add(ofl_cnt, 1,
                                               __ATOMIC_RELAXED, __HIP_MEMORY_SCOPE_AGENT);
                if (o < OFL_MAX) { st_coh_i(&ofl_v[o], cc[i]); st_coh_i(&ofl_row[o], rr[i]); }
            }
        }
    }
    gbar(grp, ++bar);

    // ---- Role setup: 4 roles (lanes 4k..4k+3), 8 slots each ----
    const int g = tx >> 2, q = tx & 3;
    const int v = bx * NPB + g;
    const bool active = (g < NPB);               // v < 20000 by construction
    float dposv = 0.0f, invd = 0.0f;
    int   cnt = 0, ocnt = 0;
    int   er[8];
    if (active) {
        cnt = min(ld_coh_i(&fill[v]), CAP);
        // two int4 plain loads; 32B-aligned (v*128 + q*32 bytes); lines fresh
        // (st_coh-written, never read pre-barrier) -> cannot be cached stale
        const int4* pb = (const int4*)&pcsc[v * CAP + q * 8];
        int4 a = pb[0], b = pb[1];
        er[0]=a.x; er[1]=a.y; er[2]=a.z; er[3]=a.w;
        er[4]=b.x; er[5]=b.y; er[6]=b.z; er[7]=b.w;
        if (q == 0) {
            dposv  = fmaxf(demands[v], 0.0f);
            int dv = ld_coh_i(&deg[v]);
            invd   = (dv > 0) ? (1.0f / (float)dv) : 0.0f;  // V[v] unread if deg==0
            ocnt   = ld_coh_i(ofl_cnt);                     // expected 0
        }
        // -- V2-direct role partial: sum_s relu(d[er_s]) * (1/deg[er_s]) --
        float p = 0.0f;
        #pragma unroll
        for (int s = 0; s < 8; ++s)
            if (q * 8 + s < cnt)
                p += fmaxf(demands[er[s]], 0.0f)
                   * (1.0f / (float)ld_coh_i(&deg[er[s]]));
        // butterfly over the 4-lane group (all partners active: g-uniform)
        p += __shfl_xor(p, 1);
        p += __shfl_xor(p, 2);
        if (q == 0) {
            float acc = dposv + p;
            if (ocnt > 0) {                             // exactness fallback
                for (int o = 0; o < ocnt && o < OFL_MAX; ++o)
                    if (ld_coh_i(&ofl_v[o]) == v) {
                        int r = ld_coh_i(&ofl_row[o]);
                        acc += fmaxf(demands[r], 0.0f)
                             * (1.0f / (float)ld_coh_i(&deg[r]));
                    }
            }
            st_coh(&V0[v], acc * invd);                 // publish V2
        }
    }
    gbar(grp, ++bar);

    // ---- 8 rounds j=3..10: predicated role gathers + shuffle reduce ----
    #pragma unroll 1
    for (int j = 3; j <= 10; ++j) {
        const float* Vp = (j & 1) ? V0 : V1b;   // j odd reads V0 (even level)
        float*       Vn = (j & 1) ? V1b : V0;
        if (active) {
            float p = 0.0f;
            #pragma unroll
            for (int s = 0; s < 8; ++s)
                if (q * 8 + s < cnt) p += ld_coh(&Vp[er[s]]);   // predicated
            p += __shfl_xor(p, 1);
            p += __shfl_xor(p, 2);
            if (q == 0) {
                float acc = dposv + p;
                if (ocnt > 0) {                 // exactness fallback, ~never
                    for (int o = 0; o < ocnt && o < OFL_MAX; ++o)
                        if (ld_coh_i(&ofl_v[o]) == v)
                            acc += ld_coh(&Vp[ld_coh_i(&ofl_row[o])]);
                }
                st_coh(&Vn[v], acc * invd);     // publish V_j
            }
        }
        gbar(grp, ++bar);
    }

    // ---- out[e] = V_10[row_e] (j=10 wrote V0); r4 in registers ----
    if (bld) {
        float4 o4;
        o4.x = ld_coh(&V0[r4.x]);
        o4.y = ld_coh(&V0[r4.y]);
        o4.z = ld_coh(&V0[r4.z]);
        o4.w = ld_coh(&V0[r4.w]);
        ((float4*)out)[m] = o4;
    }
}

extern "C" void kernel_launch(void* const* d_in, const int* in_sizes, int n_in,
                              void* d_out, int out_size, void* d_ws, size_t ws_size,
                              hipStream_t stream) {
    const float* demands  = (const float*)d_in[1];
    const int*   edge_row = (const int*)d_in[2];
    const int*   edge_col = (const int*)d_in[3];
    float*       out      = (float*)d_out;

    char* ws = (char*)d_ws;
    auto take = [&](size_t bytes) {
        void* p = (void*)ws;
        ws += (bytes + 127) & ~size_t(127);
        return p;
    };
    // ---- zero zone (one 0x00 memset) ----
    char* zone0 = ws;
    int*   deg     = (int*)  take(N_NODES * 4);
    int*   fill    = (int*)  take(N_NODES * 4);
    float* V0      = (float*)take(NP1 * 4);
    float* V1b     = (float*)take(NP1 * 4);
    int*   ofl_cnt = (int*)  take(4);
    int*   grp     = (int*)  take(NLINE * 32 * 4);
    size_t zone0_bytes = (size_t)(ws - zone0);
    // ---- uninitialized zone ----
    int*   pcsc    = (int*)  take((size_t)N_NODES * CAP * 4);
    int*   ofl_v   = (int*)  take(OFL_MAX * 4);
    int*   ofl_row = (int*)  take(OFL_MAX * 4);

    hipMemsetAsync(zone0, 0x00, zone0_bytes, stream);
    mcf_fused<<<NBLK, NTHR, 0, stream>>>(demands, edge_row, edge_col, out,
                                         deg, fill, V0, V1b, pcsc,
                                         ofl_cnt, ofl_v, ofl_row, grp);
}

// Round 9
// 128.415 us; speedup vs baseline: 1.0194x; 1.0194x over previous
//
#include <hip/hip_runtime.h>

// SparseMCFModel — flow depends only on demands/edge_row/edge_col (GAT/GRU dead).
//   V_1[v] = relu(d[v])/deg[v]
//   V_j[v] = (relu(d[v]) + sum_{e:col=v} V_{j-1}[row_e]) / deg[v],  j=2..10
//   out[e] = V_10[row_e]
//
// r23 = r21 (48.8us champion) with ONE variable changed — the reduce:
//   3 roles x 8 slots + LDS part[] + per-round __syncthreads
//     -> 2 roles x 12 slots + one __shfl_xor(p,1)   (lanes 2k,2k+1 same wave)
//   CAP stays 24; role q reads pcsc[v*24 + q*12] (byte off v*96+{0,48}, both
//   16B-aligned -> 3x int4). Removes LDS buffer + 9 syncthreads.
// DECOMPOSITION RATIONALE: r22 bundled {shuffle-reduce, CAP 32, 160 blocks}
//   and regressed to 57.2us. This isolates the shuffle-reduce on the r21
//   geometry. If it regresses too, r21 is the structural floor -> revert.
// POST-MORTEM series: r15/r16 dataflow convoys; r17/r18 small-grid invariance;
//  r19 per-round fence storms; r20 one-fence-pair +37us & plain-store build
//  saves no writes; r22 grid/CAP bundle regression.
// Coherence rules (r6-r14 proven): cross-block mutable data ONLY via agent-
//  scope atomic ld/st; deg/fill read ld_coh (memset may leave stale-zero L2
//  copies); pcsc st_coh-written, plain-read post-barrier (fresh lines);
//  demands/edge_* immutable -> plain cached. All spins watchdog-bounded.

#define N_NODES 20000
#define N_EDGES 200000
#define NBLK 128
#define NTHR 512
#define NPB 157                            // nodes per block (128*157 = 20096)
#define CAP 24                             // padded in-edge slots (2 roles x 12)
#define NQUAD 50000                        // N_EDGES/4 int4 quads
#define QPB 391                            // quads per block (391*128 = 50048)
#define OFL_MAX 4096
#define NP1 (N_NODES + 1)
#define SPIN_MAX 65536                     // watchdog: never hang, fail loud

__device__ __forceinline__ float ld_coh(const float* p) {
    return __hip_atomic_load(p, __ATOMIC_RELAXED, __HIP_MEMORY_SCOPE_AGENT);
}
__device__ __forceinline__ int ld_coh_i(const int* p) {
    return __hip_atomic_load(p, __ATOMIC_RELAXED, __HIP_MEMORY_SCOPE_AGENT);
}
__device__ __forceinline__ void st_coh(float* p, float v) {
    __hip_atomic_store(p, v, __ATOMIC_RELAXED, __HIP_MEMORY_SCOPE_AGENT);
}
__device__ __forceinline__ void st_coh_i(int* p, int v) {
    __hip_atomic_store(p, v, __ATOMIC_RELAXED, __HIP_MEMORY_SCOPE_AGENT);
}

// Distributed-arrival barrier (r14/r21-exact): 8 padded lines, 16 serialized
// RMWs each (lines in parallel); poller sums all 8 with ILP. Watchdog.
__device__ __forceinline__ void gbar(int* grp, int ord) {
    __syncthreads();
    if (threadIdx.x == 0) {
        __hip_atomic_fetch_add(&grp[(blockIdx.x & 7) * 32], 1,
                               __ATOMIC_RELAXED, __HIP_MEMORY_SCOPE_AGENT);
        const int target = NBLK * ord;
        for (int t = 0; t < SPIN_MAX; ++t) {
            int s = 0;
            #pragma unroll
            for (int g = 0; g < 8; ++g)
                s += __hip_atomic_load(&grp[g * 32], __ATOMIC_RELAXED,
                                       __HIP_MEMORY_SCOPE_AGENT);
            if (s >= target) break;
            __builtin_amdgcn_s_sleep(1);
        }
    }
    __syncthreads();
}

__global__ __launch_bounds__(NTHR)
void mcf_fused(const float* __restrict__ demands,
               const int* __restrict__ edge_row,   // int4-aligned
               const int* __restrict__ edge_col,
               float* __restrict__ out,
               int* __restrict__ deg,       // [N]   zeroed
               int* __restrict__ fill,      // [N]   zeroed
               float* __restrict__ V0,      // [N+1] zeroed
               float* __restrict__ V1b,     // [N+1] zeroed
               int* __restrict__ pcsc,      // [N*CAP]
               int* __restrict__ ofl_cnt,   // [1]   zeroed
               int* __restrict__ ofl_v,     // [OFL_MAX]
               int* __restrict__ ofl_row,   // [OFL_MAX]
               int* __restrict__ grp)       // [8*32] zeroed
{
    const int tx = threadIdx.x, bx = blockIdx.x;
    int bar = 0;

    // ---- Build (r21-exact): int4 edge loads, deg/fill atomics, st_coh pcsc ----
    const int m = bx * QPB + tx;                  // this thread's quad
    const bool bld = (tx < QPB) && (m < NQUAD);
    int4 r4 = {0, 0, 0, 0};
    if (bld) {
        r4 = ((const int4*)edge_row)[m];
        int4 c4 = ((const int4*)edge_col)[m];
        int rr[4] = {r4.x, r4.y, r4.z, r4.w};
        int cc[4] = {c4.x, c4.y, c4.z, c4.w};
        #pragma unroll
        for (int i = 0; i < 4; ++i) {
            __hip_atomic_fetch_add(&deg[rr[i]], 1, __ATOMIC_RELAXED, __HIP_MEMORY_SCOPE_AGENT);
            int idx = __hip_atomic_fetch_add(&fill[cc[i]], 1,
                                             __ATOMIC_RELAXED, __HIP_MEMORY_SCOPE_AGENT);
            if (idx < CAP) {
                st_coh_i(&pcsc[cc[i] * CAP + idx], rr[i]);   // 2-line-local
            } else {
                int o = __hip_atomic_fetch_add(ofl_cnt, 1,
                                               __ATOMIC_RELAXED, __HIP_MEMORY_SCOPE_AGENT);
                if (o < OFL_MAX) { st_coh_i(&ofl_v[o], cc[i]); st_coh_i(&ofl_row[o], rr[i]); }
            }
        }
    }
    gbar(grp, ++bar);

    // ---- Role setup: 2 roles (lanes 2k,2k+1), 12 slots each ----
    const int g = tx >> 1, q = tx & 1;
    const int v = bx * NPB + g;
    const bool active = (g < NPB) && (v < N_NODES);
    float dposv = 0.0f, invd = 0.0f;
    int   cnt = 0, ocnt = 0;
    int   er[12];
    if (active) {
        cnt = min(ld_coh_i(&fill[v]), CAP);
        // three int4 plain loads; byte offset v*96 + q*48 (16B-aligned);
        // lines fresh (st_coh-written, never read pre-barrier) -> not stale
        const int4* pb = (const int4*)&pcsc[v * CAP + q * 12];
        int4 a = pb[0], b = pb[1], c = pb[2];
        er[0]=a.x; er[1]=a.y; er[2]=a.z;  er[3]=a.w;
        er[4]=b.x; er[5]=b.y; er[6]=b.z;  er[7]=b.w;
        er[8]=c.x; er[9]=c.y; er[10]=c.z; er[11]=c.w;
        if (q == 0) {
            dposv  = fmaxf(demands[v], 0.0f);
            int dv = ld_coh_i(&deg[v]);
            invd   = (dv > 0) ? (1.0f / (float)dv) : 0.0f;  // V[v] unread if deg==0
            ocnt   = ld_coh_i(ofl_cnt);                     // expected 0
        }
        // -- V2-direct role partial: sum_s relu(d[er_s]) * (1/deg[er_s]) --
        float p = 0.0f;
        #pragma unroll
        for (int s = 0; s < 12; ++s)
            if (q * 12 + s < cnt)
                p += fmaxf(demands[er[s]], 0.0f)
                   * (1.0f / (float)ld_coh_i(&deg[er[s]]));
        p += __shfl_xor(p, 1);                  // pair reduce (g-uniform pair)
        if (q == 0) {
            float acc = dposv + p;
            if (ocnt > 0) {                             // exactness fallback
                for (int o = 0; o < ocnt && o < OFL_MAX; ++o)
                    if (ld_coh_i(&ofl_v[o]) == v) {
                        int r = ld_coh_i(&ofl_row[o]);
                        acc += fmaxf(demands[r], 0.0f)
                             * (1.0f / (float)ld_coh_i(&deg[r]));
                    }
            }
            st_coh(&V0[v], acc * invd);                 // publish V2
        }
    }
    gbar(grp, ++bar);

    // ---- 8 rounds j=3..10: predicated role gathers + pair shuffle reduce ----
    #pragma unroll 1
    for (int j = 3; j <= 10; ++j) {
        const float* Vp = (j & 1) ? V0 : V1b;   // j odd reads V0 (even level)
        float*       Vn = (j & 1) ? V1b : V0;
        if (active) {
            float p = 0.0f;
            #pragma unroll
            for (int s = 0; s < 12; ++s)
                if (q * 12 + s < cnt) p += ld_coh(&Vp[er[s]]);   // predicated
            p += __shfl_xor(p, 1);
            if (q == 0) {
                float acc = dposv + p;
                if (ocnt > 0) {                 // exactness fallback, ~never
                    for (int o = 0; o < ocnt && o < OFL_MAX; ++o)
                        if (ld_coh_i(&ofl_v[o]) == v)
                            acc += ld_coh(&Vp[ld_coh_i(&ofl_row[o])]);
                }
                st_coh(&Vn[v], acc * invd);     // publish V_j
            }
        }
        gbar(grp, ++bar);
    }

    // ---- out[e] = V_10[row_e] (j=10 wrote V0); r4 in registers ----
    if (bld) {
        float4 o4;
        o4.x = ld_coh(&V0[r4.x]);
        o4.y = ld_coh(&V0[r4.y]);
        o4.z = ld_coh(&V0[r4.z]);
        o4.w = ld_coh(&V0[r4.w]);
        ((float4*)out)[m] = o4;
    }
}

extern "C" void kernel_launch(void* const* d_in, const int* in_sizes, int n_in,
                              void* d_out, int out_size, void* d_ws, size_t ws_size,
                              hipStream_t stream) {
    const float* demands  = (const float*)d_in[1];
    const int*   edge_row = (const int*)d_in[2];
    const int*   edge_col = (const int*)d_in[3];
    float*       out      = (float*)d_out;

    char* ws = (char*)d_ws;
    auto take = [&](size_t bytes) {
        void* p = (void*)ws;
        ws += (bytes + 127) & ~size_t(127);
        return p;
    };
    // ---- zero zone (one 0x00 memset) ----
    char* zone0 = ws;
    int*   deg     = (int*)  take(N_NODES * 4);
    int*   fill    = (int*)  take(N_NODES * 4);
    float* V0      = (float*)take(NP1 * 4);
    float* V1b     = (float*)take(NP1 * 4);
    int*   ofl_cnt = (int*)  take(4);
    int*   grp     = (int*)  take(8 * 32 * 4);
    size_t zone0_bytes = (size_t)(ws - zone0);
    // ---- uninitialized zone ----
    int*   pcsc    = (int*)  take((size_t)N_NODES * CAP * 4);
    int*   ofl_v   = (int*)  take(OFL_MAX * 4);
    int*   ofl_row = (int*)  take(OFL_MAX * 4);

    hipMemsetAsync(zone0, 0x00, zone0_bytes, stream);
    mcf_fused<<<NBLK, NTHR, 0, stream>>>(demands, edge_row, edge_col, out,
                                         deg, fill, V0, V1b, pcsc,
                                         ofl_cnt, ofl_v, ofl_row, grp);
}

// Round 10
// 121.054 us; speedup vs baseline: 1.0813x; 1.0608x over previous
//
#include <hip/hip_runtime.h>

// SparseMCFModel — flow depends only on demands/edge_row/edge_col (GAT/GRU dead).
//   V_1[v] = relu(d[v])/deg[v]
//   V_j[v] = (relu(d[v]) + sum_{e:col=v} V_{j-1}[row_e]) / deg[v],  j=2..10
//   out[e] = V_10[row_e]
//
// r24 = r21 EXACT (measured champion: 48.8us kernel / 121.2us bench).
// Final post-mortem ledger (why this structure, with every deviation measured):
//   r15/r16 dataflow chain:      65.0us  (wave convoys ~7us/level; barriers win)
//   r17/r18 split small grid:    56.8us  (invariant to gather path & 40/80 blk)
//   r19 per-round agent fences: 154.2us  (L2 wbinv broadcast storms)
//   r20 one fence pair:          87.6us  (+37us; plain-store build saves no
//                                         writes — pcsc scatter dirties ~12MB
//                                         across 8 non-coherent L2s either way)
//   r22 CAP32/160blk bundle:     57.2us
//   r23 2-role shuffle reduce:   53.8us  (round time = longest per-lane
//                                         coherent-load chain: 12 > 8; the LDS
//                                         reduce hides under the vmcnt drain)
//   r21 V2-direct (THIS):        48.8us  (the one win: -1 round, -1 barrier,
//                                         bitwise-identical terms)
// Structure: r14 skeleton — 128 blk x 512 thr; 3 roles x 8 slots per node
// (471/512 threads), predicated ld_coh gathers, LDS 3-way reduce, st_coh
// publish; distributed-arrival barrier (8 lines x 16 RMWs); write-through
// st_coh CSC build; V2 computed directly from demands/deg in setup.
// Counters at champion: 5-6% HBM, 1.4% VALU, 0 bank conflicts — latency/
// sync-structured (10 serial global exchanges + 10 grid barriers + atomic
// build), not resource-bound; all per-component attacks regressed.
// Coherence rules (r6-r14 proven): cross-block mutable data ONLY via agent-
// scope atomic ld/st; deg/fill read ld_coh (memset may leave stale-zero L2
// copies); pcsc st_coh-written, plain-read post-barrier (fresh lines);
// demands/edge_* immutable -> plain cached. All spins watchdog-bounded.

#define N_NODES 20000
#define N_EDGES 200000
#define NBLK 128
#define NTHR 512
#define NPB 157                            // nodes per block (128*157 = 20096)
#define CAP 24                             // padded in-edge slots per node
#define NQUAD 50000                        // N_EDGES/4 int4 quads
#define QPB 391                            // quads per block (391*128 = 50048)
#define OFL_MAX 4096
#define NP1 (N_NODES + 1)
#define SPIN_MAX 65536                     // watchdog: never hang, fail loud

__device__ __forceinline__ float ld_coh(const float* p) {
    return __hip_atomic_load(p, __ATOMIC_RELAXED, __HIP_MEMORY_SCOPE_AGENT);
}
__device__ __forceinline__ int ld_coh_i(const int* p) {
    return __hip_atomic_load(p, __ATOMIC_RELAXED, __HIP_MEMORY_SCOPE_AGENT);
}
__device__ __forceinline__ void st_coh(float* p, float v) {
    __hip_atomic_store(p, v, __ATOMIC_RELAXED, __HIP_MEMORY_SCOPE_AGENT);
}
__device__ __forceinline__ void st_coh_i(int* p, int v) {
    __hip_atomic_store(p, v, __ATOMIC_RELAXED, __HIP_MEMORY_SCOPE_AGENT);
}

// Distributed-arrival barrier: 8 padded lines, 16 serialized RMWs each (lines
// in parallel); poller sums all 8 with ILP. Watchdog-bounded.
__device__ __forceinline__ void gbar(int* grp, int ord) {
    __syncthreads();
    if (threadIdx.x == 0) {
        __hip_atomic_fetch_add(&grp[(blockIdx.x & 7) * 32], 1,
                               __ATOMIC_RELAXED, __HIP_MEMORY_SCOPE_AGENT);
        const int target = NBLK * ord;
        for (int t = 0; t < SPIN_MAX; ++t) {
            int s = 0;
            #pragma unroll
            for (int g = 0; g < 8; ++g)
                s += __hip_atomic_load(&grp[g * 32], __ATOMIC_RELAXED,
                                       __HIP_MEMORY_SCOPE_AGENT);
            if (s >= target) break;
            __builtin_amdgcn_s_sleep(1);
        }
    }
    __syncthreads();
}

__global__ __launch_bounds__(NTHR)
void mcf_fused(const float* __restrict__ demands,
               const int* __restrict__ edge_row,   // int4-aligned
               const int* __restrict__ edge_col,
               float* __restrict__ out,
               int* __restrict__ deg,       // [N]   zeroed
               int* __restrict__ fill,      // [N]   zeroed
               float* __restrict__ V0,      // [N+1] zeroed
               float* __restrict__ V1b,     // [N+1] zeroed
               int* __restrict__ pcsc,      // [N*CAP]
               int* __restrict__ ofl_cnt,   // [1]   zeroed
               int* __restrict__ ofl_v,     // [OFL_MAX]
               int* __restrict__ ofl_row,   // [OFL_MAX]
               int* __restrict__ grp)       // [8*32] zeroed
{
    const int tx = threadIdx.x, bx = blockIdx.x;
    int bar = 0;

    __shared__ float part[NTHR];

    // ---- Build: int4 edge loads, deg/fill atomics, st_coh pcsc scatter ----
    const int m = bx * QPB + tx;                  // this thread's quad
    const bool bld = (tx < QPB) && (m < NQUAD);
    int4 r4 = {0, 0, 0, 0};
    if (bld) {
        r4 = ((const int4*)edge_row)[m];
        int4 c4 = ((const int4*)edge_col)[m];
        int rr[4] = {r4.x, r4.y, r4.z, r4.w};
        int cc[4] = {c4.x, c4.y, c4.z, c4.w};
        #pragma unroll
        for (int i = 0; i < 4; ++i) {
            __hip_atomic_fetch_add(&deg[rr[i]], 1, __ATOMIC_RELAXED, __HIP_MEMORY_SCOPE_AGENT);
            int idx = __hip_atomic_fetch_add(&fill[cc[i]], 1,
                                             __ATOMIC_RELAXED, __HIP_MEMORY_SCOPE_AGENT);
            if (idx < CAP) {
                st_coh_i(&pcsc[cc[i] * CAP + idx], rr[i]);   // 2-line-local
            } else {
                int o = __hip_atomic_fetch_add(ofl_cnt, 1,
                                               __ATOMIC_RELAXED, __HIP_MEMORY_SCOPE_AGENT);
                if (o < OFL_MAX) { st_coh_i(&ofl_v[o], cc[i]); st_coh_i(&ofl_row[o], rr[i]); }
            }
        }
    }
    gbar(grp, ++bar);

    // ---- Role setup + V2-direct (replaces the V1 publish round) ----
    const int g = tx / 3, q = tx - 3 * g;
    const int v = bx * NPB + g;
    const bool active = (g < NPB) && (v < N_NODES);
    float dposv = 0.0f, invd = 0.0f;
    int   cnt = 0, ocnt = 0;
    int   er[8];
    if (active) {
        cnt = min(ld_coh_i(&fill[v]), CAP);
        // two int4 plain loads; 32B-aligned; lines fresh (st_coh-written,
        // never read pre-barrier) -> cannot be cached stale
        const int4* pb = (const int4*)&pcsc[v * CAP + q * 8];
        int4 a = pb[0], b = pb[1];
        er[0]=a.x; er[1]=a.y; er[2]=a.z; er[3]=a.w;
        er[4]=b.x; er[5]=b.y; er[6]=b.z; er[7]=b.w;
        if (q == 0) {
            dposv  = fmaxf(demands[v], 0.0f);
            int dv = ld_coh_i(&deg[v]);
            invd   = (dv > 0) ? (1.0f / (float)dv) : 0.0f;  // V[v] unread if deg==0
            ocnt   = ld_coh_i(ofl_cnt);                     // expected 0
        }
        // V2-direct role partial: sum_s relu(d[er_s]) * (1/deg[er_s]) —
        // each term == the V1 value the source's owner would have published
        // (same fmaxf * (1.0f/deg) expression); slot order == round order.
        float p = 0.0f;
        #pragma unroll
        for (int s = 0; s < 8; ++s)
            if (q * 8 + s < cnt)
                p += fmaxf(demands[er[s]], 0.0f)
                   * (1.0f / (float)ld_coh_i(&deg[er[s]]));
        part[tx] = p;
    }
    __syncthreads();
    if (active && q == 0) {
        float acc = dposv + part[tx] + part[tx + 1] + part[tx + 2];
        if (ocnt > 0) {                                 // exactness fallback
            for (int o = 0; o < ocnt && o < OFL_MAX; ++o)
                if (ld_coh_i(&ofl_v[o]) == v) {
                    int r = ld_coh_i(&ofl_row[o]);
                    acc += fmaxf(demands[r], 0.0f)
                         * (1.0f / (float)ld_coh_i(&deg[r]));
                }
        }
        st_coh(&V0[v], acc * invd);                     // publish V2
    }
    gbar(grp, ++bar);

    // ---- 8 rounds j=3..10: predicated role gathers + LDS 3-way reduce ----
    #pragma unroll 1
    for (int j = 3; j <= 10; ++j) {
        const float* Vp = (j & 1) ? V0 : V1b;   // j odd reads V0 (even level)
        float*       Vn = (j & 1) ? V1b : V0;
        if (active) {
            float p = 0.0f;
            #pragma unroll
            for (int s = 0; s < 8; ++s)
                if (q * 8 + s < cnt) p += ld_coh(&Vp[er[s]]);   // predicated
            part[tx] = p;
        }
        __syncthreads();
        if (active && q == 0) {
            float acc = dposv + part[tx] + part[tx + 1] + part[tx + 2];
            if (ocnt > 0) {                     // exactness fallback, ~never
                for (int o = 0; o < ocnt && o < OFL_MAX; ++o)
                    if (ld_coh_i(&ofl_v[o]) == v) acc += ld_coh(&Vp[ld_coh_i(&ofl_row[o])]);
            }
            st_coh(&Vn[v], acc * invd);         // publish V_j
        }
        gbar(grp, ++bar);
    }

    // ---- out[e] = V_10[row_e] (j=10 wrote V0); r4 in registers ----
    if (bld) {
        float4 o4;
        o4.x = ld_coh(&V0[r4.x]);
        o4.y = ld_coh(&V0[r4.y]);
        o4.z = ld_coh(&V0[r4.z]);
        o4.w = ld_coh(&V0[r4.w]);
        ((float4*)out)[m] = o4;
    }
}

extern "C" void kernel_launch(void* const* d_in, const int* in_sizes, int n_in,
                              void* d_out, int out_size, void* d_ws, size_t ws_size,
                              hipStream_t stream) {
    const float* demands  = (const float*)d_in[1];
    const int*   edge_row = (const int*)d_in[2];
    const int*   edge_col = (const int*)d_in[3];
    float*       out      = (float*)d_out;

    char* ws = (char*)d_ws;
    auto take = [&](size_t bytes) {
        void* p = (void*)ws;
        ws += (bytes + 127) & ~size_t(127);
        return p;
    };
    // ---- zero zone (one 0x00 memset) ----
    char* zone0 = ws;
    int*   deg     = (int*)  take(N_NODES * 4);
    int*   fill    = (int*)  take(N_NODES * 4);
    float* V0      = (float*)take(NP1 * 4);
    float* V1b     = (float*)take(NP1 * 4);
    int*   ofl_cnt = (int*)  take(4);
    int*   grp     = (int*)  take(8 * 32 * 4);
    size_t zone0_bytes = (size_t)(ws - zone0);
    // ---- uninitialized zone ----
    int*   pcsc    = (int*)  take((size_t)N_NODES * CAP * 4);
    int*   ofl_v   = (int*)  take(OFL_MAX * 4);
    int*   ofl_row = (int*)  take(OFL_MAX * 4);

    hipMemsetAsync(zone0, 0x00, zone0_bytes, stream);
    mcf_fused<<<NBLK, NTHR, 0, stream>>>(demands, edge_row, edge_col, out,
                                         deg, fill, V0, V1b, pcsc,
                                         ofl_cnt, ofl_v, ofl_row, grp);
}